// Round 2
// baseline (217.467 us; speedup 1.0000x reference)
//
#include <hip/hip_runtime.h>

// Problem constants
#define B_ 256
#define T_ 64
#define N_ 128
#define H_ 128
#define G3 384   // 3*H (gate rows)
#define K2 256   // 2*H (packed matvec K range: [agg ; prev])

// Workspace layout (float offsets)
#define WS_G    0                    // G table: 384*384  (b_ih + W_ih[:, :H] @ emb[e])
#define WS_PW   (WS_G + G3*G3)       // packed transposed weights: 256*384
#define WS_NZC  (WS_PW + K2*G3)     // 128 ints: nonzero counts
#define WS_NZP  (WS_NZC + 128)      // 128*128 int2 pairs (n, w bits)

// ---------------------------------------------------------------------------
// Single prep kernel, 768 blocks x 384 threads, role by blockIdx:
//   [0,384):   G[e][j] = b_ih[j] + sum_k W_ih[j][k] * emb[e][k]
//   [384,512): nz list for adj row (bid-384)
//   [512,768): PW[k][j] = k<128 ? W_ih[j][128+k] : W_hh[j][k-128]
// ---------------------------------------------------------------------------
__global__ void __launch_bounds__(384) prep(
        const float* __restrict__ W_ih, const float* __restrict__ W_hh,
        const float* __restrict__ emb,  const float* __restrict__ b_ih,
        const float* __restrict__ adj,  float* __restrict__ ws) {
    const int bid = blockIdx.x;
    if (bid < 384) {
        __shared__ float es[H_];
        const int e = bid, j = threadIdx.x;
        if (j < H_) es[j] = emb[e * H_ + j];
        __syncthreads();
        float acc = b_ih[j];
        const float4* wrow = (const float4*)(W_ih + j * K2);  // row j, cols [0,128)
        #pragma unroll 8
        for (int i = 0; i < 32; ++i) {
            float4 w = wrow[i];
            acc += w.x * es[4*i];       // separate statements: same association
            acc += w.y * es[4*i + 1];   // as round-1 scalar loop
            acc += w.z * es[4*i + 2];
            acc += w.w * es[4*i + 3];
        }
        (ws + WS_G)[e * G3 + j] = acc;
    } else if (bid < 512) {
        __shared__ float row[N_];
        const int r = bid - 384;
        if (threadIdx.x < N_) row[threadIdx.x] = adj[r * N_ + threadIdx.x];
        __syncthreads();
        if (threadIdx.x == 0) {
            int*  nzc = (int*)(ws + WS_NZC);
            int2* nzp = (int2*)(ws + WS_NZP);
            int cnt = 0;
            for (int n = 0; n < N_; ++n) {
                float w = row[n];
                if (w != 0.0f) { nzp[r * N_ + cnt] = make_int2(n, __float_as_int(w)); ++cnt; }
            }
            int cnt4 = (cnt + 3) & ~3;
            for (int i = cnt; i < cnt4; ++i) nzp[r * N_ + i] = make_int2(0, 0); // w=0 pad
            nzc[r] = cnt;
        }
    } else {
        const int k = bid - 512, j = threadIdx.x;
        (ws + WS_PW)[k * G3 + j] = (k < H_) ? W_ih[j * K2 + H_ + k]
                                            : W_hh[j * H_ + (k - H_)];
    }
}

// ---------------------------------------------------------------------------
// Main kernel: one block per batch element, T-step recurrence, 2 barriers/step.
// 512 threads = (t in [0,128)) x (q in [0,4)); thread holds 192 weights in VGPRs.
// Phase A: matvec partials (q<2 read agg buffer, q>=2 read h[task] directly),
//          q3 stages next nz row, wave0 finalizes previous step's logit.
// Phase B: q0/q1 compute hnew (dup); q0 writes h row + red; q1 computes agg
//          for step s+1 (substituting local hnew for the just-updated row —
//          bit-exact, no extra barrier); q2 stores previous logits row.
// ---------------------------------------------------------------------------
__global__ void __launch_bounds__(512, 2) gkt_main(
        const int* __restrict__ task_seq, const int* __restrict__ status_seq,
        const float* __restrict__ b_hh,   const float* __restrict__ w_pred,
        const float* __restrict__ b_pred, const float* __restrict__ ws,
        float* __restrict__ out) {
    __shared__ __align__(16) float h_lds[N_ * H_];   // 64 KB state
    __shared__ __align__(16) float aggbuf[H_];       // agg vector for current step
    __shared__ float pl[4 * G3];                     // matvec partials [q][gate*128+t]
    __shared__ float red[H_];                        // logit-dot partials
    __shared__ float Ll[N_];                         // running logits
    __shared__ int2  nzbuf[N_];                      // staged nz list (next step's task)
    __shared__ int   nz_cnt;
    __shared__ int   tasks_l[T_], stats_l[T_];

    const int b   = blockIdx.x;
    const int tid = threadIdx.x;
    const int t   = tid & 127;
    const int q   = tid >> 7;

    const float* G   = ws + WS_G;
    const float* PW  = ws + WS_PW;
    const int*   nzc = (const int*)(ws + WS_NZC);
    const int2*  nzp = (const int2*)(ws + WS_NZP);

    // ---- prologue: register-resident weights (coalesced: lane stride 1 in j)
    float wr[64], wz[64], wn[64];
    {
        const float* base = PW + (q * 64) * G3 + t;
        #pragma unroll
        for (int kk = 0; kk < 64; ++kk) {
            wr[kk] = base[kk * G3];
            wz[kk] = base[kk * G3 + 128];
            wn[kk] = base[kk * G3 + 256];
        }
    }
    const float bp = b_pred[0];
    float bhr = 0.f, bhz = 0.f, bhn = 0.f, wpt = 0.f;
    if (q < 2) { bhr = b_hh[t]; bhz = b_hh[128 + t]; bhn = b_hh[256 + t]; }
    if (q == 0) wpt = w_pred[t];

    // ---- init state
    for (int i = tid; i < N_ * H_; i += 512) h_lds[i] = 0.0f;
    if (tid < T_)            tasks_l[tid]       = task_seq[b * T_ + tid];
    else if (tid < 2 * T_)   stats_l[tid - T_]  = status_seq[b * T_ + (tid - T_)];
    if (tid < N_) { Ll[tid] = bp; aggbuf[tid] = 0.0f; }   // h0=0 -> agg_0=0, logits=b_pred
    __syncthreads();

    for (int s = 0; s < T_; ++s) {
        const int task = tasks_l[s];

        // ---- Phase A ----------------------------------------------------
        float prevreg = 0.f;
        if (q < 2) prevreg = h_lds[task * H_ + t];   // prev state, pre-update
        {
            const float* vbase = (q < 2) ? (aggbuf + q * 64)
                                         : (h_lds + task * H_ + (q - 2) * 64);
            float pr = 0.f, pz = 0.f, pn = 0.f;
            #pragma unroll
            for (int kk = 0; kk < 64; kk += 4) {
                const float4 v = *(const float4*)(vbase + kk);  // wave-uniform LDS read
                pr += wr[kk] * v.x + wr[kk + 1] * v.y + wr[kk + 2] * v.z + wr[kk + 3] * v.w;
                pz += wz[kk] * v.x + wz[kk + 1] * v.y + wz[kk + 2] * v.z + wz[kk + 3] * v.w;
                pn += wn[kk] * v.x + wn[kk + 1] * v.y + wn[kk + 2] * v.z + wn[kk + 3] * v.w;
            }
            pl[q * G3 + t]       = pr;
            pl[q * G3 + 128 + t] = pz;
            pl[q * G3 + 256 + t] = pn;
        }
        if (q == 3 && s + 1 < T_) {                  // stage next step's nz row
            const int tn = tasks_l[s + 1];
            nzbuf[t] = nzp[tn * N_ + t];
            if (t == 0) nz_cnt = nzc[tn];
        }
        if (tid < 64 && s > 0) {                     // finalize logit of step s-1
            float x = red[tid] + red[tid + 64];
            #pragma unroll
            for (int off = 32; off > 0; off >>= 1) x += __shfl_xor(x, off, 64);
            if (tid == 0) Ll[tasks_l[s - 1]] = x + bp;
        }
        __syncthreads();

        // ---- Phase B ----------------------------------------------------
        if (q < 2) {
            const int e = task * 3 + stats_l[s];
            const float g0 = G[e * G3 + t];
            const float g1 = G[e * G3 + 128 + t];
            const float g2 = G[e * G3 + 256 + t];
            float sr  = g0 + bhr + pl[0*G3 + t] + pl[1*G3 + t] + pl[2*G3 + t] + pl[3*G3 + t];
            float sz  = g1 + bhz + pl[0*G3 + 128 + t] + pl[1*G3 + 128 + t]
                                 + pl[2*G3 + 128 + t] + pl[3*G3 + 128 + t];
            float in_ = g2 + pl[0*G3 + 256 + t] + pl[1*G3 + 256 + t];   // i_n (k<128)
            float hn_ = bhn + pl[2*G3 + 256 + t] + pl[3*G3 + 256 + t];  // h_n (k>=128)
            float r = 1.0f / (1.0f + expf(-sr));
            float z = 1.0f / (1.0f + expf(-sz));
            float n = tanhf(in_ + r * hn_);
            float hnew = (1.0f - z) * n + z * prevreg;
            if (q == 0) {
                h_lds[task * H_ + t] = hnew;
                red[t] = hnew * wpt;
            } else if (s + 1 < T_) {                 // agg for step s+1
                float acc = 0.0f;
                const int cnt4 = (nz_cnt + 3) & ~3;
                for (int i = 0; i < cnt4; i += 4) {
                    int2 p0 = nzbuf[i], p1 = nzbuf[i+1], p2 = nzbuf[i+2], p3 = nzbuf[i+3];
                    float h0 = (p0.x == task) ? hnew : h_lds[p0.x * H_ + t];
                    float h1 = (p1.x == task) ? hnew : h_lds[p1.x * H_ + t];
                    float h2 = (p2.x == task) ? hnew : h_lds[p2.x * H_ + t];
                    float h3 = (p3.x == task) ? hnew : h_lds[p3.x * H_ + t];
                    acc += __int_as_float(p0.y) * h0;
                    acc += __int_as_float(p1.y) * h1;
                    acc += __int_as_float(p2.y) * h2;
                    acc += __int_as_float(p3.y) * h3;
                }
                aggbuf[t] = acc;
            }
        } else if (q == 2) {
            if (s > 0) out[(size_t)b * T_ * N_ + (size_t)(s - 1) * N_ + t] = Ll[t];
        }
        __syncthreads();
    }

    // ---- epilogue: final logit update, last logits row, final hidden state
    if (tid < 64) {
        float x = red[tid] + red[tid + 64];
        #pragma unroll
        for (int off = 32; off > 0; off >>= 1) x += __shfl_xor(x, off, 64);
        if (tid == 0) Ll[tasks_l[T_ - 1]] = x + bp;
    }
    __syncthreads();
    if (tid < N_) out[(size_t)b * T_ * N_ + (size_t)(T_ - 1) * N_ + tid] = Ll[tid];
    {
        float4* dst = (float4*)(out + (size_t)B_ * T_ * N_ + (size_t)b * N_ * H_);
        const float4* src = (const float4*)h_lds;
        for (int i = tid; i < N_ * H_ / 4; i += 512) dst[i] = src[i];
    }
}

// ---------------------------------------------------------------------------
extern "C" void kernel_launch(void* const* d_in, const int* in_sizes, int n_in,
                              void* d_out, int out_size, void* d_ws, size_t ws_size,
                              hipStream_t stream) {
    const int*   task = (const int*)d_in[0];
    const int*   stat = (const int*)d_in[1];
    const float* adj  = (const float*)d_in[2];
    const float* emb  = (const float*)d_in[3];
    const float* Wih  = (const float*)d_in[4];
    const float* Whh  = (const float*)d_in[5];
    const float* bhh  = (const float*)d_in[7];
    const float* wp   = (const float*)d_in[8];
    const float* bp   = (const float*)d_in[9];
    const float* bih  = (const float*)d_in[6];
    float* out = (float*)d_out;
    float* ws  = (float*)d_ws;

    prep    <<<768, 384, 0, stream>>>(Wih, Whh, emb, bih, adj, ws);
    gkt_main<<<256, 512, 0, stream>>>(task, stat, bhh, wp, bp, ws, out);
}

// Round 3
// 216.015 us; speedup vs baseline: 1.0067x; 1.0067x over previous
//
#include <hip/hip_runtime.h>

// Problem constants
#define B_ 256
#define T_ 64
#define N_ 128
#define H_ 128
#define G3 384   // 3*H (gate rows)
#define K2 256   // 2*H (packed matvec K range: [agg ; prev])

// Workspace layout (float offsets)
#define WS_G    0                    // G table: 384*384  (b_ih + W_ih[:, :H] @ emb[e])
#define WS_PW   (WS_G + G3*G3)       // packed transposed weights: 256*384
#define WS_NZC  (WS_PW + K2*G3)      // 128 ints: nonzero counts
#define WS_NZP  (WS_NZC + 128)       // 128*128 int2 pairs (n, w bits)

// ---------------------------------------------------------------------------
// Single prep kernel, 768 blocks x 384 threads, role by blockIdx:
//   [0,384):   G[e][j] = b_ih[j] + sum_k W_ih[j][k] * emb[e][k]
//   [384,512): nz list for adj row (bid-384)
//   [512,768): PW[k][j] = k<128 ? W_ih[j][128+k] : W_hh[j][k-128]
// ---------------------------------------------------------------------------
__global__ void __launch_bounds__(384) prep(
        const float* __restrict__ W_ih, const float* __restrict__ W_hh,
        const float* __restrict__ emb,  const float* __restrict__ b_ih,
        const float* __restrict__ adj,  float* __restrict__ ws) {
    const int bid = blockIdx.x;
    if (bid < 384) {
        __shared__ float es[H_];
        const int e = bid, j = threadIdx.x;
        if (j < H_) es[j] = emb[e * H_ + j];
        __syncthreads();
        float acc = b_ih[j];
        const float4* wrow = (const float4*)(W_ih + j * K2);  // row j, cols [0,128)
        #pragma unroll 8
        for (int i = 0; i < 32; ++i) {
            float4 w = wrow[i];
            acc += w.x * es[4*i];
            acc += w.y * es[4*i + 1];
            acc += w.z * es[4*i + 2];
            acc += w.w * es[4*i + 3];
        }
        (ws + WS_G)[e * G3 + j] = acc;
    } else if (bid < 512) {
        __shared__ float row[N_];
        const int r = bid - 384;
        if (threadIdx.x < N_) row[threadIdx.x] = adj[r * N_ + threadIdx.x];
        __syncthreads();
        if (threadIdx.x == 0) {
            int*  nzc = (int*)(ws + WS_NZC);
            int2* nzp = (int2*)(ws + WS_NZP);
            int cnt = 0;
            for (int n = 0; n < N_; ++n) {
                float w = row[n];
                if (w != 0.0f) { nzp[r * N_ + cnt] = make_int2(n, __float_as_int(w)); ++cnt; }
            }
            int cnt4 = (cnt + 3) & ~3;
            for (int i = cnt; i < cnt4; ++i) nzp[r * N_ + i] = make_int2(0, 0); // w=0 pad
            nzc[r] = cnt;
        }
    } else {
        const int k = bid - 512, j = threadIdx.x;
        (ws + WS_PW)[k * G3 + j] = (k < H_) ? W_ih[j * K2 + H_ + k]
                                            : W_hh[j * H_ + (k - H_)];
    }
}

// ---------------------------------------------------------------------------
// Main kernel: one block per batch element, 768 threads = 12 waves (3/SIMD,
// hard VGPR cap 170). Thread (c = tid/192, j2 = tid%192) owns output rows
// {j2, 192+j2} restricted to K-quarter c (64 elems) -> 128 weights in VGPRs
// (guaranteed resident: ~155 regs total < 170 cap).
// Phase A: matvec partials (c<2 read aggbuf, c>=2 read h[task] directly);
//          side: stage next nz row (waves 8-9), finalize prev logit (wave 0),
//          gate groups prefetch prevreg + G row.
// Phase B: waves 0-1 gates + h-write + red; waves 6-7 dup gates + agg(s+1)
//          with hnew substitution; waves 3-4 store prev logits row.
// ---------------------------------------------------------------------------
__global__ void __launch_bounds__(768, 3) gkt_main(
        const int* __restrict__ task_seq, const int* __restrict__ status_seq,
        const float* __restrict__ b_hh,   const float* __restrict__ w_pred,
        const float* __restrict__ b_pred, const float* __restrict__ ws,
        float* __restrict__ out) {
    __shared__ __align__(16) float h_lds[N_ * H_];   // 64 KB state
    __shared__ __align__(16) float aggbuf[H_];       // agg vector for current step
    __shared__ float pl[4 * G3];                     // partials [c][row]
    __shared__ float red[H_];                        // logit-dot partials
    __shared__ float Ll[N_];                         // running logits
    __shared__ int2  nzbuf[N_];                      // staged nz list (next task)
    __shared__ int   nz_cnt;
    __shared__ int   tasks_l[T_], stats_l[T_];

    const int b   = blockIdx.x;
    const int tid = threadIdx.x;
    const int c   = tid / 192;           // K-quarter, wave-uniform (192 = 3 waves)
    const int j2  = tid - c * 192;       // row pair id in [0,192)

    const float* G   = ws + WS_G;
    const float* PW  = ws + WS_PW;
    const int*   nzc = (const int*)(ws + WS_NZC);
    const int2*  nzp = (const int2*)(ws + WS_NZP);

    // ---- prologue: 128 register-resident weights, fully unrolled loads
    float wA[64], wB[64];
    {
        const float* baseA = PW + (c * 64) * G3 + j2;
        #pragma unroll
        for (int kk = 0; kk < 64; ++kk) {
            wA[kk] = baseA[kk * G3];
            wB[kk] = baseA[kk * G3 + 192];
        }
    }

    const float bp = b_pred[0];
    const bool gate0 = (tid < 128);
    const bool gate1 = (tid >= 384 && tid < 512);
    const int  tg = gate0 ? tid : (tid - 384);   // valid only for gate groups
    float bhr = 0.f, bhz = 0.f, bhn = 0.f, wpt = 0.f;
    if (gate0 || gate1) { bhr = b_hh[tg]; bhz = b_hh[128 + tg]; bhn = b_hh[256 + tg]; }
    if (gate0) wpt = w_pred[tid];

    // ---- init
    for (int i = tid; i < N_ * H_; i += 768) h_lds[i] = 0.0f;
    if (tid < T_)          tasks_l[tid]      = task_seq[b * T_ + tid];
    else if (tid < 2*T_)   stats_l[tid - T_] = status_seq[b * T_ + (tid - T_)];
    if (tid >= 128 && tid < 256) { Ll[tid-128] = bp; aggbuf[tid-128] = 0.0f; }
    __syncthreads();

    for (int s = 0; s < T_; ++s) {
        const int task = tasks_l[s];

        // ---- Phase A ----------------------------------------------------
        float prevreg = 0.f, g0 = 0.f, g1 = 0.f, g2 = 0.f;
        if (gate0 || gate1) {                        // prefetch for phase B
            prevreg = h_lds[task * H_ + tg];
            const int e = task * 3 + stats_l[s];
            g0 = G[e * G3 + tg];
            g1 = G[e * G3 + 128 + tg];
            g2 = G[e * G3 + 256 + tg];
        }
        {
            const float4* vb = (const float4*)((c < 2) ? (aggbuf + c * 64)
                                                       : (h_lds + task * H_ + (c - 2) * 64));
            float a0 = 0.f, a1 = 0.f, c0 = 0.f, c1 = 0.f;
            #pragma unroll
            for (int i = 0; i < 16; i += 2) {
                const float4 v = vb[i];
                a0 += wA[4*i+0]*v.x; a0 += wA[4*i+1]*v.y; a0 += wA[4*i+2]*v.z; a0 += wA[4*i+3]*v.w;
                c0 += wB[4*i+0]*v.x; c0 += wB[4*i+1]*v.y; c0 += wB[4*i+2]*v.z; c0 += wB[4*i+3]*v.w;
                const float4 u = vb[i+1];
                a1 += wA[4*i+4]*u.x; a1 += wA[4*i+5]*u.y; a1 += wA[4*i+6]*u.z; a1 += wA[4*i+7]*u.w;
                c1 += wB[4*i+4]*u.x; c1 += wB[4*i+5]*u.y; c1 += wB[4*i+6]*u.z; c1 += wB[4*i+7]*u.w;
            }
            pl[c * G3 + j2]       = a0 + a1;
            pl[c * G3 + 192 + j2] = c0 + c1;
        }
        if (tid >= 512 && tid < 640 && s + 1 < T_) { // stage next step's nz row
            const int t = tid - 512, tn = tasks_l[s + 1];
            nzbuf[t] = nzp[tn * N_ + t];
            if (t == 0) nz_cnt = nzc[tn];
        }
        if (tid < 64 && s > 0) {                     // finalize logit of step s-1
            float x = red[tid] + red[tid + 64];
            #pragma unroll
            for (int off = 32; off > 0; off >>= 1) x += __shfl_xor(x, off, 64);
            if (tid == 0) Ll[tasks_l[s - 1]] = x + bp;
        }
        __syncthreads();

        // ---- Phase B ----------------------------------------------------
        if (gate0 || gate1) {
            float sr  = g0 + bhr + pl[tg] + pl[G3 + tg] + pl[2*G3 + tg] + pl[3*G3 + tg];
            float sz  = g1 + bhz + pl[128 + tg] + pl[G3 + 128 + tg]
                                 + pl[2*G3 + 128 + tg] + pl[3*G3 + 128 + tg];
            float in_ = g2 + pl[256 + tg] + pl[G3 + 256 + tg];          // i_n (k<128)
            float hn_ = bhn + pl[2*G3 + 256 + tg] + pl[3*G3 + 256 + tg];// h_n (k>=128)
            float r = 1.0f / (1.0f + expf(-sr));
            float z = 1.0f / (1.0f + expf(-sz));
            float n = tanhf(in_ + r * hn_);
            float hnew = (1.0f - z) * n + z * prevreg;
            if (gate0) {
                h_lds[task * H_ + tg] = hnew;
                red[tg] = hnew * wpt;
            } else if (s + 1 < T_) {                 // agg for step s+1
                float acc = 0.0f;
                const int cnt4 = (nz_cnt + 3) & ~3;
                for (int i = 0; i < cnt4; i += 4) {
                    int2 p0 = nzbuf[i], p1 = nzbuf[i+1], p2 = nzbuf[i+2], p3 = nzbuf[i+3];
                    float h0 = (p0.x == task) ? hnew : h_lds[p0.x * H_ + tg];
                    float h1 = (p1.x == task) ? hnew : h_lds[p1.x * H_ + tg];
                    float h2 = (p2.x == task) ? hnew : h_lds[p2.x * H_ + tg];
                    float h3 = (p3.x == task) ? hnew : h_lds[p3.x * H_ + tg];
                    acc += __int_as_float(p0.y) * h0;
                    acc += __int_as_float(p1.y) * h1;
                    acc += __int_as_float(p2.y) * h2;
                    acc += __int_as_float(p3.y) * h3;
                }
                aggbuf[tg] = acc;
            }
        } else if (tid >= 192 && tid < 320) {
            if (s > 0) out[(size_t)b * T_ * N_ + (size_t)(s - 1) * N_ + (tid - 192)] = Ll[tid - 192];
        }
        __syncthreads();
    }

    // ---- epilogue: final logit update, last logits row, final hidden state
    if (tid < 64) {
        float x = red[tid] + red[tid + 64];
        #pragma unroll
        for (int off = 32; off > 0; off >>= 1) x += __shfl_xor(x, off, 64);
        if (tid == 0) Ll[tasks_l[T_ - 1]] = x + bp;
    }
    __syncthreads();
    if (tid < N_) out[(size_t)b * T_ * N_ + (size_t)(T_ - 1) * N_ + tid] = Ll[tid];
    {
        float4* dst = (float4*)(out + (size_t)B_ * T_ * N_ + (size_t)b * N_ * H_);
        const float4* src = (const float4*)h_lds;
        for (int i = tid; i < N_ * H_ / 4; i += 768) dst[i] = src[i];
    }
}

// ---------------------------------------------------------------------------
extern "C" void kernel_launch(void* const* d_in, const int* in_sizes, int n_in,
                              void* d_out, int out_size, void* d_ws, size_t ws_size,
                              hipStream_t stream) {
    const int*   task = (const int*)d_in[0];
    const int*   stat = (const int*)d_in[1];
    const float* adj  = (const float*)d_in[2];
    const float* emb  = (const float*)d_in[3];
    const float* Wih  = (const float*)d_in[4];
    const float* Whh  = (const float*)d_in[5];
    const float* bih  = (const float*)d_in[6];
    const float* bhh  = (const float*)d_in[7];
    const float* wp   = (const float*)d_in[8];
    const float* bp   = (const float*)d_in[9];
    float* out = (float*)d_out;
    float* ws  = (float*)d_ws;

    prep    <<<768, 384, 0, stream>>>(Wih, Whh, emb, bih, adj, ws);
    gkt_main<<<256, 768, 0, stream>>>(task, stat, bhh, wp, bp, ws, out);
}